// Round 2
// baseline (366.865 us; speedup 1.0000x reference)
//
#include <hip/hip_runtime.h>

#define B_   256
#define I_   1152
#define N_   10
#define P_   9216      // 8 * 1152
#define NO_  160       // 10 * 16
#define NBLK 1280

typedef unsigned short u16;
typedef short s8v __attribute__((ext_vector_type(8)));
typedef float f4v __attribute__((ext_vector_type(4)));

__device__ inline float bf2f(u16 u){
  unsigned v = ((unsigned)u) << 16; float f; __builtin_memcpy(&f, &v, 4); return f;
}
__device__ inline u16 f2bf(float f){
  unsigned b; __builtin_memcpy(&b, &f, 4);
  b += 0x7fffu + ((b >> 16) & 1u);   // RNE
  return (u16)(b >> 16);
}

// ---------------------------------------------------------------------------
// k_prep: as in the 132 µs version, plus barrier-state zeroing (block 0).
//   blocks [0,800):  W transpose -> Wt bf16; [0,45) zero bij; [45,205) zero sA.
//   blocks [800,3104): x fp32 -> bf16 xbp[b][p] + xpb[p][b] (LDS transpose).
__global__ void k_prep(const float* __restrict__ x, const float* __restrict__ W,
                       u16* __restrict__ xbp, u16* __restrict__ xpb,
                       u16* __restrict__ Wt, float* __restrict__ bij,
                       float* __restrict__ sA, int* __restrict__ bar){
  __shared__ float tile[32][36];
  int t = threadIdx.x, u = blockIdx.x;
  if (u < 800){
    if (u == 0){                         // barrier state: 16 leaf lines + root + gen
      for (int z = t; z < 576; z += 256) bar[z] = 0;
    }
    if (u < 45) bij[u*256 + t] = 0.f;
    else if (u < 205) sA[(u - 45)*256 + t] = 0.f;
    int q = u / 5, ic = u - (u/5)*5;
    int n = q >> 4, o = q & 15;
    int i = ic*256 + t;
    if (i < I_){
      const float* src = W + (size_t)i*1280 + n*128 + o*8;
      float4 a = *reinterpret_cast<const float4*>(src);
      float4 b = *reinterpret_cast<const float4*>(src + 4);
      float vv[8] = {a.x,a.y,a.z,a.w,b.x,b.y,b.z,b.w};
      #pragma unroll
      for (int k = 0; k < 8; ++k)
        Wt[(size_t)q*P_ + (size_t)k*I_ + i] = f2bf(vv[k] * 0.03f);
    }
  } else {
    int b2 = u - 800;
    int tb = b2 & 7, tp = b2 >> 3;
    int b0 = tb << 5, p0 = tp << 5;
    int r = t >> 3, c4 = (t & 7) << 2;
    float4 v = *reinterpret_cast<const float4*>(x + (size_t)(b0 + r)*P_ + p0 + c4);
    *reinterpret_cast<float4*>(&tile[r][c4]) = v;
    uint2 pk;
    pk.x = (unsigned)f2bf(v.x) | ((unsigned)f2bf(v.y) << 16);
    pk.y = (unsigned)f2bf(v.z) | ((unsigned)f2bf(v.w) << 16);
    *reinterpret_cast<uint2*>(xbp + (size_t)(b0 + r)*P_ + p0 + c4) = pk;
    __syncthreads();
    float f0 = tile[c4+0][r], f1 = tile[c4+1][r], f2 = tile[c4+2][r], f3 = tile[c4+3][r];
    uint2 pk2;
    pk2.x = (unsigned)f2bf(f0) | ((unsigned)f2bf(f1) << 16);
    pk2.y = (unsigned)f2bf(f2) | ((unsigned)f2bf(f3) << 16);
    *reinterpret_cast<uint2*>(xpb + (size_t)(p0 + r)*B_ + b0 + c4) = pk2;
  }
}

// ---------------------------------------------------------------------------
// Software grid barrier (normal launch; all 1280 blocks co-resident:
// LDS 21248 B -> 7 blocks/CU, launch_bounds(128,4) caps VGPR at 128 ->
// capacity 1792 >= 1280). Two-level: 16 padded leaf counters (80 arrivals)
// -> root (16) -> generation bump. SEQ_CST agent RMWs publish prior plain
// stores (wbl2); acquire fence on exit invalidates L1 + stale per-XCD L2.
// bar layout: leaf li at bar[li*32]; root at bar[512]; gen at bar[544].
__device__ inline void gbar(int* bar, int bid){
  __syncthreads();
  if (threadIdx.x == 0){
    int* gen = bar + 544;
    int g = __hip_atomic_load(gen, __ATOMIC_SEQ_CST, __HIP_MEMORY_SCOPE_AGENT);
    int* leaf = bar + ((bid & 15) << 5);
    if (__hip_atomic_fetch_add(leaf, 1, __ATOMIC_SEQ_CST, __HIP_MEMORY_SCOPE_AGENT) == 79){
      __hip_atomic_store(leaf, 0, __ATOMIC_SEQ_CST, __HIP_MEMORY_SCOPE_AGENT);
      if (__hip_atomic_fetch_add(bar + 512, 1, __ATOMIC_SEQ_CST, __HIP_MEMORY_SCOPE_AGENT) == 15){
        __hip_atomic_store(bar + 512, 0, __ATOMIC_SEQ_CST, __HIP_MEMORY_SCOPE_AGENT);
        __hip_atomic_fetch_add(gen, 1, __ATOMIC_SEQ_CST, __HIP_MEMORY_SCOPE_AGENT);
      }
    }
    while (__hip_atomic_load(gen, __ATOMIC_RELAXED, __HIP_MEMORY_SCOPE_AGENT) == g)
      __builtin_amdgcn_s_sleep(2);
    __builtin_amdgcn_fence(__ATOMIC_ACQUIRE, "agent");
  }
  __syncthreads();
}

// ---------------------------------------------------------------------------
union LdsU {
  struct { u16 Bt[16][592]; float c[576]; } S;   // 21248 B
  u16 vl[32][264];                               // 16896 B
};

__device__ inline void phase_S(int t, int bid,
    const u16* __restrict__ xbp, const u16* __restrict__ Wt,
    const float* __restrict__ bij, float* __restrict__ s_cur,
    float* __restrict__ s_zero, LdsU* lds)
{
  int bx2 = bid & 7, n = (bid >> 3) % 10, kc = bid / 80;
  if (s_zero && t < 32) s_zero[bid*32 + t] = 0.f;
  int i0 = (kc & 1) * 576;

  for (int j = t; j < 576; j += 128){
    const float* br = bij + (size_t)(i0 + j)*N_;
    float l0 = br[0], l1 = br[1], l2 = br[2], l3 = br[3], l4 = br[4];
    float l5 = br[5], l6 = br[6], l7 = br[7], l8 = br[8], l9 = br[9];
    float mx = fmaxf(fmaxf(fmaxf(fmaxf(l0,l1),fmaxf(l2,l3)),
                           fmaxf(fmaxf(l4,l5),fmaxf(l6,l7))), fmaxf(l8,l9));
    float e0=__expf(l0-mx), e1=__expf(l1-mx), e2=__expf(l2-mx), e3=__expf(l3-mx), e4=__expf(l4-mx);
    float e5=__expf(l5-mx), e6=__expf(l6-mx), e7=__expf(l7-mx), e8=__expf(l8-mx), e9=__expf(l9-mx);
    float se = e0+e1+e2+e3+e4+e5+e6+e7+e8+e9;
    float ev[10] = {e0,e1,e2,e3,e4,e5,e6,e7,e8,e9};
    lds->S.c[j] = ev[n] / se;
  }
  __syncthreads();

  for (int u = t; u < 1152; u += 128){
    int r = u / 72, cb = (u - r*72) * 8;
    uint4 w = *reinterpret_cast<const uint4*>(Wt + (size_t)(n*16 + r)*P_ + kc*576 + cb);
    float4 c0 = *reinterpret_cast<const float4*>(&lds->S.c[cb]);
    float4 c1 = *reinterpret_cast<const float4*>(&lds->S.c[cb + 4]);
    uint4 rr;
    rr.x = (unsigned)f2bf(bf2f(w.x & 0xffff)*c0.x) | ((unsigned)f2bf(bf2f(w.x >> 16)*c0.y) << 16);
    rr.y = (unsigned)f2bf(bf2f(w.y & 0xffff)*c0.z) | ((unsigned)f2bf(bf2f(w.y >> 16)*c0.w) << 16);
    rr.z = (unsigned)f2bf(bf2f(w.z & 0xffff)*c1.x) | ((unsigned)f2bf(bf2f(w.z >> 16)*c1.y) << 16);
    rr.w = (unsigned)f2bf(bf2f(w.w & 0xffff)*c1.z) | ((unsigned)f2bf(bf2f(w.w >> 16)*c1.w) << 16);
    *reinterpret_cast<uint4*>(&lds->S.Bt[r][cb]) = rr;
  }
  __syncthreads();

  int wid = t >> 6, l = t & 63, lo = l & 15, quad = l >> 4;
  int b0 = bx2*32 + wid*16;
  const s8v* ap = reinterpret_cast<const s8v*>(xbp + (size_t)(b0 + lo)*P_ + kc*576 + quad*8);
  f4v acc0 = {0.f,0.f,0.f,0.f}, acc1 = {0.f,0.f,0.f,0.f};
  #pragma unroll
  for (int s = 0; s < 9; ++s){
    s8v a0 = ap[8*s];
    s8v b0v = *reinterpret_cast<const s8v*>(&lds->S.Bt[lo][quad*8 + 64*s]);
    s8v a1 = ap[8*s + 4];
    s8v b1v = *reinterpret_cast<const s8v*>(&lds->S.Bt[lo][quad*8 + 64*s + 32]);
    acc0 = __builtin_amdgcn_mfma_f32_16x16x32_bf16(a0, b0v, acc0, 0, 0, 0);
    acc1 = __builtin_amdgcn_mfma_f32_16x16x32_bf16(a1, b1v, acc1, 0, 0, 0);
  }
  f4v acc = acc0 + acc1;
  int r0 = quad << 2;
  #pragma unroll
  for (int r = 0; r < 4; ++r)
    atomicAdd(&s_cur[(size_t)(b0 + r0 + r)*NO_ + n*16 + lo], acc[r]);
}

__device__ inline void phase_G(int t, int bid,
    const u16* __restrict__ xpb, const float* __restrict__ s,
    const u16* __restrict__ Wt, float* __restrict__ bij, LdsU* lds)
{
  int qp = bid >> 8;                    // 0..4
  #pragma unroll
  for (int h = 0; h < 2; ++h){
    int b = t + h*128;
    #pragma unroll
    for (int nn = 0; nn < 2; ++nn){
      const float* sr = s + (size_t)b*NO_ + (qp*2 + nn)*16;
      float4 s0 = *reinterpret_cast<const float4*>(sr);
      float4 s1 = *reinterpret_cast<const float4*>(sr + 4);
      float4 s2 = *reinterpret_cast<const float4*>(sr + 8);
      float4 s3 = *reinterpret_cast<const float4*>(sr + 12);
      float sq = s0.x*s0.x+s0.y*s0.y+s0.z*s0.z+s0.w*s0.w
               + s1.x*s1.x+s1.y*s1.y+s1.z*s1.z+s1.w*s1.w
               + s2.x*s2.x+s2.y*s2.y+s2.z*s2.z+s2.w*s2.w
               + s3.x*s3.x+s3.y*s3.y+s3.z*s3.z+s3.w*s3.w;
      float scale = sqrtf(sq) / (1.0f + sq);
      float sv[16] = {s0.x,s0.y,s0.z,s0.w,s1.x,s1.y,s1.z,s1.w,
                      s2.x,s2.y,s2.z,s2.w,s3.x,s3.y,s3.z,s3.w};
      #pragma unroll
      for (int o = 0; o < 16; ++o)
        lds->vl[nn*16 + o][b] = f2bf(sv[o] * scale);
    }
  }
  __syncthreads();

  int wv = t >> 6, l = t & 63, lo = l & 15, quad = l >> 4;
  for (int u = (bid & 255)*2 + wv; u < 576; u += 512){
    int p0 = u << 4;
    const s8v* ap = reinterpret_cast<const s8v*>(xpb + (size_t)(p0 + lo)*B_ + quad*8);
    f4v acc0 = {0.f,0.f,0.f,0.f}, acc1 = {0.f,0.f,0.f,0.f};
    #pragma unroll
    for (int st = 0; st < 8; ++st){
      s8v a  = ap[4*st];
      s8v b0 = *reinterpret_cast<const s8v*>(&lds->vl[lo]     [st*32 + quad*8]);
      s8v b1 = *reinterpret_cast<const s8v*>(&lds->vl[16 + lo][st*32 + quad*8]);
      acc0 = __builtin_amdgcn_mfma_f32_16x16x32_bf16(a, b0, acc0, 0, 0, 0);
      acc1 = __builtin_amdgcn_mfma_f32_16x16x32_bf16(a, b1, acc1, 0, 0, 0);
    }
    int ib = p0 % 1152;                 // p-tile never spans k (1152%16==0)
    #pragma unroll
    for (int sb = 0; sb < 2; ++sb){
      f4v acc = sb ? acc1 : acc0;
      int n = qp*2 + sb;
      const u16* wp = Wt + (size_t)(n*16 + lo)*P_ + p0 + (quad << 2);
      ushort4 w4 = *reinterpret_cast<const ushort4*>(wp);
      float v0 = acc[0]*bf2f(w4.x), v1 = acc[1]*bf2f(w4.y);
      float v2 = acc[2]*bf2f(w4.z), v3 = acc[3]*bf2f(w4.w);
      #pragma unroll
      for (int m = 8; m >= 1; m >>= 1){
        v0 += __shfl_xor(v0, m, 16);
        v1 += __shfl_xor(v1, m, 16);
        v2 += __shfl_xor(v2, m, 16);
        v3 += __shfl_xor(v3, m, 16);
      }
      if (lo == 0){
        int i = ib + (quad << 2);
        atomicAdd(&bij[(i+0)*N_ + n], v0 * (1.f/256.f));
        atomicAdd(&bij[(i+1)*N_ + n], v1 * (1.f/256.f));
        atomicAdd(&bij[(i+2)*N_ + n], v2 * (1.f/256.f));
        atomicAdd(&bij[(i+3)*N_ + n], v3 * (1.f/256.f));
      }
    }
  }
}

__global__ __launch_bounds__(128, 4) void k_route(
    const u16* __restrict__ xbp, const u16* __restrict__ xpb,
    const u16* __restrict__ Wt, float* __restrict__ bij,
    float* __restrict__ sA, float* __restrict__ sB,
    float* __restrict__ out, int* __restrict__ bar)
{
  __shared__ LdsU lds;
  int t = threadIdx.x, bid = blockIdx.x;

  // ---- iter0 S: c == 0.1 uniform -> s = 0.1*(x . Wt^T). B-frags straight
  // from bf16 Wt (same indexing as Bt), scale in fp32 epilogue. Zeroes sB.
  {
    int bx2 = bid & 7, n = (bid >> 3) % 10, kc = bid / 80;
    if (t < 32) sB[bid*32 + t] = 0.f;
    int wid = t >> 6, l = t & 63, lo = l & 15, quad = l >> 4;
    int b0 = bx2*32 + wid*16;
    const s8v* ap = reinterpret_cast<const s8v*>(xbp + (size_t)(b0 + lo)*P_ + kc*576 + quad*8);
    const s8v* bp = reinterpret_cast<const s8v*>(Wt  + (size_t)(n*16 + lo)*P_ + kc*576 + quad*8);
    f4v acc0 = {0.f,0.f,0.f,0.f}, acc1 = {0.f,0.f,0.f,0.f};
    #pragma unroll
    for (int s = 0; s < 9; ++s){
      acc0 = __builtin_amdgcn_mfma_f32_16x16x32_bf16(ap[8*s],     bp[8*s],     acc0, 0, 0, 0);
      acc1 = __builtin_amdgcn_mfma_f32_16x16x32_bf16(ap[8*s + 4], bp[8*s + 4], acc1, 0, 0, 0);
    }
    f4v acc = acc0 + acc1;
    int r0 = quad << 2;
    #pragma unroll
    for (int r = 0; r < 4; ++r)
      atomicAdd(&sA[(size_t)(b0 + r0 + r)*NO_ + n*16 + lo], acc[r] * 0.1f);
  }
  gbar(bar, bid);

  phase_G(t, bid, xpb, sA, Wt, bij, &lds);      // iter0 agreement
  gbar(bar, bid);

  phase_S(t, bid, xbp, Wt, bij, sB, sA, &lds);  // iter1 s -> sB, zero sA
  gbar(bar, bid);

  phase_G(t, bid, xpb, sB, Wt, bij, &lds);      // iter1 agreement
  gbar(bar, bid);

  phase_S(t, bid, xbp, Wt, bij, sA, nullptr, &lds); // iter2 s -> sA
  gbar(bar, bid);

  // ---- final squash -> out (2560 rows of 16; first 320 blocks)
  if (bid < 320){
    int o = t & 15, rl = t >> 4;
    int rowid = bid*8 + rl;               // b*10+n
    int b = rowid / 10, n = rowid - b*10;
    size_t idx = (size_t)b*NO_ + n*16 + o;
    float sv = sA[idx];
    float sq = sv * sv;
    #pragma unroll
    for (int m = 8; m >= 1; m >>= 1) sq += __shfl_xor(sq, m, 16);
    out[idx] = sv * sqrtf(sq) / (1.0f + sq);
  }
}

// ---------------------------------------------------------------------------
extern "C" void kernel_launch(void* const* d_in, const int* in_sizes, int n_in,
                              void* d_out, int out_size, void* d_ws, size_t ws_size,
                              hipStream_t stream){
  (void)in_sizes; (void)n_in; (void)out_size; (void)ws_size;
  const float* x = (const float*)d_in[0];   // (256, 8, 1152)
  const float* W = (const float*)d_in[1];   // (1, 1152, 10, 16, 8)
  float* out = (float*)d_out;               // (256, 10, 16, 1) fp32

  float* sA  = (float*)d_ws;                // 40960 fp32
  float* sB  = sA + 40960;                  // 40960
  float* bij = sB + 40960;                  // 11520
  u16* xbp = (u16*)(bij + 11520);           // 2359296 bf16
  u16* xpb = xbp + 2359296;                 // 2359296
  u16* Wt  = xpb + 2359296;                 // 1474560
  int* bar = (int*)(Wt + 1474560);          // 576 ints (barrier state)

  k_prep<<<3104, 256, 0, stream>>>(x, W, xbp, xpb, Wt, bij, sA, bar);
  k_route<<<NBLK, 128, 0, stream>>>(xbp, xpb, Wt, bij, sA, sB, out, bar);
}

// Round 3
// 185.704 us; speedup vs baseline: 1.9755x; 1.9755x over previous
//
#include <hip/hip_runtime.h>

#define B_   256
#define I_   1152
#define N_   10
#define P_   9216      // 8 * 1152
#define NO_  160       // 10 * 16
#define NBLK 1280

typedef unsigned short u16;
typedef short s8v __attribute__((ext_vector_type(8)));
typedef float f4v __attribute__((ext_vector_type(4)));

__device__ inline float bf2f(u16 u){
  unsigned v = ((unsigned)u) << 16; float f; __builtin_memcpy(&f, &v, 4); return f;
}
__device__ inline u16 f2bf(float f){
  unsigned b; __builtin_memcpy(&b, &f, 4);
  b += 0x7fffu + ((b >> 16) & 1u);   // RNE
  return (u16)(b >> 16);
}

// MALL-coherent payload accessors (relaxed agent atomics bypass stale L1/L2;
// values produced by device-scope atomicAdd live at the coherence point).
__device__ inline void ald2(const float* p, float& a, float& b){
  unsigned long long q = __hip_atomic_load((const unsigned long long*)p,
      __ATOMIC_RELAXED, __HIP_MEMORY_SCOPE_AGENT);
  unsigned lo = (unsigned)q, hi = (unsigned)(q >> 32);
  __builtin_memcpy(&a, &lo, 4); __builtin_memcpy(&b, &hi, 4);
}
__device__ inline float ald1(const float* p){
  unsigned u = __hip_atomic_load((const unsigned*)p,
      __ATOMIC_RELAXED, __HIP_MEMORY_SCOPE_AGENT);
  float f; __builtin_memcpy(&f, &u, 4); return f;
}
__device__ inline void ast1(float* p, float v){
  unsigned u; __builtin_memcpy(&u, &v, 4);
  __hip_atomic_store((unsigned*)p, u, __ATOMIC_RELAXED, __HIP_MEMORY_SCOPE_AGENT);
}

// swizzled c index: +2 dwords per 8 -> lane bank spread (kills 16-way conflict)
#define CIX(j) ((j) + (((j) >> 3) << 1))

// ---------------------------------------------------------------------------
// k_prep: unchanged logic; bar zero extended to 2080 ints.
__global__ void k_prep(const float* __restrict__ x, const float* __restrict__ W,
                       u16* __restrict__ xbp, u16* __restrict__ xpb,
                       u16* __restrict__ Wt, float* __restrict__ bij,
                       float* __restrict__ sA, int* __restrict__ bar){
  __shared__ float tile[32][36];
  int t = threadIdx.x, u = blockIdx.x;
  if (u < 800){
    if (u == 0){
      for (int z = t; z < 2080; z += 256) bar[z] = 0;
    }
    if (u < 45) bij[u*256 + t] = 0.f;
    else if (u < 205) sA[(u - 45)*256 + t] = 0.f;
    int q = u / 5, ic = u - (u/5)*5;
    int n = q >> 4, o = q & 15;
    int i = ic*256 + t;
    if (i < I_){
      const float* src = W + (size_t)i*1280 + n*128 + o*8;
      float4 a = *reinterpret_cast<const float4*>(src);
      float4 b = *reinterpret_cast<const float4*>(src + 4);
      float vv[8] = {a.x,a.y,a.z,a.w,b.x,b.y,b.z,b.w};
      #pragma unroll
      for (int k = 0; k < 8; ++k)
        Wt[(size_t)q*P_ + (size_t)k*I_ + i] = f2bf(vv[k] * 0.03f);
    }
  } else {
    int b2 = u - 800;
    int tb = b2 & 7, tp = b2 >> 3;
    int b0 = tb << 5, p0 = tp << 5;
    int r = t >> 3, c4 = (t & 7) << 2;
    float4 v = *reinterpret_cast<const float4*>(x + (size_t)(b0 + r)*P_ + p0 + c4);
    *reinterpret_cast<float4*>(&tile[r][c4]) = v;
    uint2 pk;
    pk.x = (unsigned)f2bf(v.x) | ((unsigned)f2bf(v.y) << 16);
    pk.y = (unsigned)f2bf(v.z) | ((unsigned)f2bf(v.w) << 16);
    *reinterpret_cast<uint2*>(xbp + (size_t)(b0 + r)*P_ + p0 + c4) = pk;
    __syncthreads();
    float f0 = tile[c4+0][r], f1 = tile[c4+1][r], f2 = tile[c4+2][r], f3 = tile[c4+3][r];
    uint2 pk2;
    pk2.x = (unsigned)f2bf(f0) | ((unsigned)f2bf(f1) << 16);
    pk2.y = (unsigned)f2bf(f2) | ((unsigned)f2bf(f3) << 16);
    *reinterpret_cast<uint2*>(xpb + (size_t)(p0 + r)*B_ + b0 + c4) = pk2;
  }
}

// ---------------------------------------------------------------------------
// Fence-free monotonic grid barrier. All RELAXED agent atomics (no implicit
// cache maintenance). __syncthreads before arrival drains vmcnt -> this
// block's MALL atomics are globally visible. Payload reads after the barrier
// are themselves MALL atomics, so no acquire fence (L2 stays warm for the
// read-only arrays). 32 leaves x 40 arrivals -> root x 32 -> 32 padded
// release words; monotonic counts, no resets, no generation race.
// bar: leaf li @ [li*32], rel li @ [1024+li*32], root @ [2048].
__device__ inline void gbar(int* bar, int bid, int ph){
  __syncthreads();
  if (threadIdx.x == 0){
    int li = bid & 31;
    if (__hip_atomic_fetch_add(bar + li*32, 1, __ATOMIC_RELAXED,
                               __HIP_MEMORY_SCOPE_AGENT) == ph*40 - 1){
      if (__hip_atomic_fetch_add(bar + 2048, 1, __ATOMIC_RELAXED,
                                 __HIP_MEMORY_SCOPE_AGENT) == ph*32 - 1){
        #pragma unroll
        for (int z = 0; z < 32; ++z)
          __hip_atomic_store(bar + 1024 + z*32, ph, __ATOMIC_RELAXED,
                             __HIP_MEMORY_SCOPE_AGENT);
      }
    }
    while (__hip_atomic_load(bar + 1024 + li*32, __ATOMIC_RELAXED,
                             __HIP_MEMORY_SCOPE_AGENT) < ph)
      __builtin_amdgcn_s_sleep(8);
  }
  __syncthreads();
}

// ---------------------------------------------------------------------------
union LdsU {
  struct { float c[740]; u16 Bt[16][592]; } S;   // 2960 + 18944 = 21904 B
  u16 vl[32][264];                               // 16896 B
};

__device__ inline void phase_S(int t, int bid,
    const u16* __restrict__ xbp, const u16* __restrict__ Wt,
    const float* __restrict__ bij, float* __restrict__ s_cur,
    float* __restrict__ s_zero, LdsU* lds)
{
  int bx2 = bid & 7, n = (bid >> 3) % 10, kc = bid / 80;
  if (s_zero && t < 32) ast1(&s_zero[bid*32 + t], 0.f);
  int i0 = (kc & 1) * 576;

  // prefetch the Wt B-tile (read-only, L2-warm) while softmax runs
  uint4 wpre[9];
  #pragma unroll
  for (int s9 = 0; s9 < 9; ++s9){
    int u = t + s9*128;
    int r = u / 72, m = u - r*72;
    wpre[s9] = *reinterpret_cast<const uint4*>(
        Wt + (size_t)(n*16 + r)*P_ + kc*576 + m*8);
  }

  // softmax: bij rows via MALL atomic loads (fresh, no L2 invalidation)
  #pragma unroll
  for (int it = 0; it < 5; ++it){
    int j = t + it*128;
    if (j < 576){
      const float* br = bij + (size_t)(i0 + j)*N_;
      float l0,l1,l2,l3,l4,l5,l6,l7,l8,l9;
      ald2(br,   l0, l1); ald2(br+2, l2, l3); ald2(br+4, l4, l5);
      ald2(br+6, l6, l7); ald2(br+8, l8, l9);
      float mx = fmaxf(fmaxf(fmaxf(fmaxf(l0,l1),fmaxf(l2,l3)),
                             fmaxf(fmaxf(l4,l5),fmaxf(l6,l7))), fmaxf(l8,l9));
      float e0=__expf(l0-mx), e1=__expf(l1-mx), e2=__expf(l2-mx), e3=__expf(l3-mx), e4=__expf(l4-mx);
      float e5=__expf(l5-mx), e6=__expf(l6-mx), e7=__expf(l7-mx), e8=__expf(l8-mx), e9=__expf(l9-mx);
      float se = e0+e1+e2+e3+e4+e5+e6+e7+e8+e9;
      float ev[10] = {e0,e1,e2,e3,e4,e5,e6,e7,e8,e9};
      lds->S.c[CIX(j)] = ev[n] / se;
    }
  }
  __syncthreads();

  // combine prefetched Wt with c (float2 reads on swizzled index: no 16-way)
  #pragma unroll
  for (int s9 = 0; s9 < 9; ++s9){
    int u = t + s9*128;
    int r = u / 72, m = u - r*72;
    const float* cp = &lds->S.c[10*m];
    float2 ca = *reinterpret_cast<const float2*>(cp);
    float2 cb = *reinterpret_cast<const float2*>(cp + 2);
    float2 cc = *reinterpret_cast<const float2*>(cp + 4);
    float2 cd = *reinterpret_cast<const float2*>(cp + 6);
    uint4 w = wpre[s9];
    uint4 rr;
    rr.x = (unsigned)f2bf(bf2f(w.x & 0xffff)*ca.x) | ((unsigned)f2bf(bf2f(w.x >> 16)*ca.y) << 16);
    rr.y = (unsigned)f2bf(bf2f(w.y & 0xffff)*cb.x) | ((unsigned)f2bf(bf2f(w.y >> 16)*cb.y) << 16);
    rr.z = (unsigned)f2bf(bf2f(w.z & 0xffff)*cc.x) | ((unsigned)f2bf(bf2f(w.z >> 16)*cc.y) << 16);
    rr.w = (unsigned)f2bf(bf2f(w.w & 0xffff)*cd.x) | ((unsigned)f2bf(bf2f(w.w >> 16)*cd.y) << 16);
    *reinterpret_cast<uint4*>(&lds->S.Bt[r][m*8]) = rr;
  }
  __syncthreads();

  int wid = t >> 6, l = t & 63, lo = l & 15, quad = l >> 4;
  int b0 = bx2*32 + wid*16;
  const s8v* ap = reinterpret_cast<const s8v*>(xbp + (size_t)(b0 + lo)*P_ + kc*576 + quad*8);
  f4v acc0 = {0.f,0.f,0.f,0.f}, acc1 = {0.f,0.f,0.f,0.f};
  #pragma unroll
  for (int s = 0; s < 9; ++s){
    s8v a0 = ap[8*s];
    s8v b0v = *reinterpret_cast<const s8v*>(&lds->S.Bt[lo][quad*8 + 64*s]);
    s8v a1 = ap[8*s + 4];
    s8v b1v = *reinterpret_cast<const s8v*>(&lds->S.Bt[lo][quad*8 + 64*s + 32]);
    acc0 = __builtin_amdgcn_mfma_f32_16x16x32_bf16(a0, b0v, acc0, 0, 0, 0);
    acc1 = __builtin_amdgcn_mfma_f32_16x16x32_bf16(a1, b1v, acc1, 0, 0, 0);
  }
  f4v acc = acc0 + acc1;
  int r0 = quad << 2;
  #pragma unroll
  for (int r = 0; r < 4; ++r)
    atomicAdd(&s_cur[(size_t)(b0 + r0 + r)*NO_ + n*16 + lo], acc[r]);
}

__device__ inline void phase_G(int t, int bid,
    const u16* __restrict__ xpb, const float* __restrict__ s,
    const u16* __restrict__ Wt, float* __restrict__ bij, LdsU* lds)
{
  int qp = bid >> 8;                    // 0..4
  #pragma unroll
  for (int h = 0; h < 2; ++h){
    int b = t + h*128;
    #pragma unroll
    for (int nn = 0; nn < 2; ++nn){
      const float* sr = s + (size_t)b*NO_ + (qp*2 + nn)*16;
      float sv[16];
      #pragma unroll
      for (int k = 0; k < 8; ++k) ald2(sr + 2*k, sv[2*k], sv[2*k+1]);
      float sq = 0.f;
      #pragma unroll
      for (int o = 0; o < 16; ++o) sq += sv[o]*sv[o];
      float scale = sqrtf(sq) / (1.0f + sq);
      #pragma unroll
      for (int o = 0; o < 16; ++o)
        lds->vl[nn*16 + o][b] = f2bf(sv[o] * scale);
    }
  }
  __syncthreads();

  int wv = t >> 6, l = t & 63, lo = l & 15, quad = l >> 4;
  for (int u = (bid & 255)*2 + wv; u < 576; u += 512){
    int p0 = u << 4;
    const s8v* ap = reinterpret_cast<const s8v*>(xpb + (size_t)(p0 + lo)*B_ + quad*8);
    f4v acc0 = {0.f,0.f,0.f,0.f}, acc1 = {0.f,0.f,0.f,0.f};
    #pragma unroll
    for (int st = 0; st < 8; ++st){
      s8v a  = ap[4*st];
      s8v b0 = *reinterpret_cast<const s8v*>(&lds->vl[lo]     [st*32 + quad*8]);
      s8v b1 = *reinterpret_cast<const s8v*>(&lds->vl[16 + lo][st*32 + quad*8]);
      acc0 = __builtin_amdgcn_mfma_f32_16x16x32_bf16(a, b0, acc0, 0, 0, 0);
      acc1 = __builtin_amdgcn_mfma_f32_16x16x32_bf16(a, b1, acc1, 0, 0, 0);
    }
    int ib = p0 % 1152;                 // p-tile never spans k (1152%16==0)
    #pragma unroll
    for (int sb = 0; sb < 2; ++sb){
      f4v acc = sb ? acc1 : acc0;
      int n = qp*2 + sb;
      const u16* wp = Wt + (size_t)(n*16 + lo)*P_ + p0 + (quad << 2);
      ushort4 w4 = *reinterpret_cast<const ushort4*>(wp);
      float v0 = acc[0]*bf2f(w4.x), v1 = acc[1]*bf2f(w4.y);
      float v2 = acc[2]*bf2f(w4.z), v3 = acc[3]*bf2f(w4.w);
      #pragma unroll
      for (int m = 8; m >= 1; m >>= 1){
        v0 += __shfl_xor(v0, m, 16);
        v1 += __shfl_xor(v1, m, 16);
        v2 += __shfl_xor(v2, m, 16);
        v3 += __shfl_xor(v3, m, 16);
      }
      if (lo == 0){
        int i = ib + (quad << 2);
        atomicAdd(&bij[(i+0)*N_ + n], v0 * (1.f/256.f));
        atomicAdd(&bij[(i+1)*N_ + n], v1 * (1.f/256.f));
        atomicAdd(&bij[(i+2)*N_ + n], v2 * (1.f/256.f));
        atomicAdd(&bij[(i+3)*N_ + n], v3 * (1.f/256.f));
      }
    }
  }
}

__global__ __launch_bounds__(128, 3) void k_route(
    const u16* __restrict__ xbp, const u16* __restrict__ xpb,
    const u16* __restrict__ Wt, float* __restrict__ bij,
    float* __restrict__ sA, float* __restrict__ sB,
    float* __restrict__ out, int* __restrict__ bar)
{
  __shared__ LdsU lds;
  int t = threadIdx.x, bid = blockIdx.x;

  // ---- iter0 S: c == 0.1 uniform -> s = 0.1*(x . Wt^T). B-frags straight
  // from bf16 Wt, scale in fp32 epilogue. Zeroes sB (atomic: MALL-visible).
  {
    int bx2 = bid & 7, n = (bid >> 3) % 10, kc = bid / 80;
    if (t < 32) ast1(&sB[bid*32 + t], 0.f);
    int wid = t >> 6, l = t & 63, lo = l & 15, quad = l >> 4;
    int b0 = bx2*32 + wid*16;
    const s8v* ap = reinterpret_cast<const s8v*>(xbp + (size_t)(b0 + lo)*P_ + kc*576 + quad*8);
    const s8v* bp = reinterpret_cast<const s8v*>(Wt  + (size_t)(n*16 + lo)*P_ + kc*576 + quad*8);
    f4v acc0 = {0.f,0.f,0.f,0.f}, acc1 = {0.f,0.f,0.f,0.f};
    #pragma unroll
    for (int s = 0; s < 9; ++s){
      acc0 = __builtin_amdgcn_mfma_f32_16x16x32_bf16(ap[8*s],     bp[8*s],     acc0, 0, 0, 0);
      acc1 = __builtin_amdgcn_mfma_f32_16x16x32_bf16(ap[8*s + 4], bp[8*s + 4], acc1, 0, 0, 0);
    }
    f4v acc = acc0 + acc1;
    int r0 = quad << 2;
    #pragma unroll
    for (int r = 0; r < 4; ++r)
      atomicAdd(&sA[(size_t)(b0 + r0 + r)*NO_ + n*16 + lo], acc[r] * 0.1f);
  }
  gbar(bar, bid, 1);

  phase_G(t, bid, xpb, sA, Wt, bij, &lds);          // iter0 agreement
  gbar(bar, bid, 2);

  phase_S(t, bid, xbp, Wt, bij, sB, sA, &lds);      // iter1 s -> sB, zero sA
  gbar(bar, bid, 3);

  phase_G(t, bid, xpb, sB, Wt, bij, &lds);          // iter1 agreement
  gbar(bar, bid, 4);

  phase_S(t, bid, xbp, Wt, bij, sA, nullptr, &lds); // iter2 s -> sA
  gbar(bar, bid, 5);

  // ---- final squash -> out (2560 rows of 16; first 320 blocks)
  if (bid < 320){
    int o = t & 15, rl = t >> 4;
    int rowid = bid*8 + rl;               // b*10+n
    int b = rowid / 10, n = rowid - b*10;
    size_t idx = (size_t)b*NO_ + n*16 + o;
    float sv = ald1(&sA[idx]);
    float sq = sv * sv;
    #pragma unroll
    for (int m = 8; m >= 1; m >>= 1) sq += __shfl_xor(sq, m, 16);
    out[idx] = sv * sqrtf(sq) / (1.0f + sq);
  }
}

// ---------------------------------------------------------------------------
extern "C" void kernel_launch(void* const* d_in, const int* in_sizes, int n_in,
                              void* d_out, int out_size, void* d_ws, size_t ws_size,
                              hipStream_t stream){
  (void)in_sizes; (void)n_in; (void)out_size; (void)ws_size;
  const float* x = (const float*)d_in[0];   // (256, 8, 1152)
  const float* W = (const float*)d_in[1];   // (1, 1152, 10, 16, 8)
  float* out = (float*)d_out;               // (256, 10, 16, 1) fp32

  float* sA  = (float*)d_ws;                // 40960 fp32
  float* sB  = sA + 40960;                  // 40960
  float* bij = sB + 40960;                  // 11520
  u16* xbp = (u16*)(bij + 11520);           // 2359296 bf16
  u16* xpb = xbp + 2359296;                 // 2359296
  u16* Wt  = xpb + 2359296;                 // 1474560
  int* bar = (int*)(Wt + 1474560);          // 2080 ints (barrier state)

  k_prep<<<3104, 256, 0, stream>>>(x, W, xbp, xpb, Wt, bij, sA, bar);
  k_route<<<NBLK, 128, 0, stream>>>(xbp, xpb, Wt, bij, sA, sB, out, bar);
}

// Round 4
// 141.262 us; speedup vs baseline: 2.5971x; 1.3146x over previous
//
#include <hip/hip_runtime.h>

#define B_   256
#define I_   1152
#define N_   10
#define P_   9216      // 8 * 1152
#define NO_  160       // 10 * 16
#define BIJS 12        // padded bij row stride (floats) -> 48B rows, 16B aligned
#define NBLK 1280

typedef unsigned short u16;
typedef short s8v __attribute__((ext_vector_type(8)));
typedef float f4v __attribute__((ext_vector_type(4)));

__device__ inline float bf2f(u16 u){
  unsigned v = ((unsigned)u) << 16; float f; __builtin_memcpy(&f, &v, 4); return f;
}
__device__ inline u16 f2bf(float f){
  unsigned b; __builtin_memcpy(&b, &f, 4);
  b += 0x7fffu + ((b >> 16) & 1u);   // RNE
  return (u16)(b >> 16);
}
// MALL-coherent scalar accessors (bypass L1/L2; atomicAdd data lives at MALL)
__device__ inline float ald1(const float* p){
  unsigned u = __hip_atomic_load((const unsigned*)p,
      __ATOMIC_RELAXED, __HIP_MEMORY_SCOPE_AGENT);
  float f; __builtin_memcpy(&f, &u, 4); return f;
}
__device__ inline void ast1(float* p, float v){
  unsigned u; __builtin_memcpy(&u, &v, 4);
  __hip_atomic_store((unsigned*)p, u, __ATOMIC_RELAXED, __HIP_MEMORY_SCOPE_AGENT);
}

// c LDS swizzle: element j stored at CIX(j); reader at 10m..10m+7 gets j=8m..8m+7
#define CIX(j) ((j) + (((j) >> 3) << 1))

// ---------------------------------------------------------------------------
// k_prep rewrite: vectorized stores everywhere. 3021 blocks x 128.
//  [0,1440):   W-part. task q = u/9, chunk = u%9 (128 i's). LDS transpose
//              [8 k][136] -> 16B coalesced Wt stores.
//  [1440,2592): x-part. 32b x 64p tile. xbp: pack 8 fp32 -> uint4 store.
//              LDS tile [32][68] fp32 -> transpose -> xpb uint4 stores.
//  [2592,2700): zero bij (13824 fl, stride-12 rows).
//  [2700,3020): zero sA (40960 fl).
//  3020:        zero bar (4128 ints).
__global__ __launch_bounds__(128) void k_prep(
    const float* __restrict__ x, const float* __restrict__ W,
    u16* __restrict__ xbp, u16* __restrict__ xpb, u16* __restrict__ Wt,
    float* __restrict__ bij, float* __restrict__ sA, int* __restrict__ bar){
  __shared__ union { u16 w[8][136]; float t[32][68]; } sm;
  int t = threadIdx.x, u = blockIdx.x;
  if (u < 1440){
    int q = u/9, ch = u - q*9;
    int n = q >> 4, o = q & 15;
    int i = ch*128 + t;
    const float* src = W + (size_t)i*1280 + n*128 + o*8;
    float4 a = *reinterpret_cast<const float4*>(src);
    float4 b = *reinterpret_cast<const float4*>(src + 4);
    float vv[8] = {a.x,a.y,a.z,a.w,b.x,b.y,b.z,b.w};
    #pragma unroll
    for (int k = 0; k < 8; ++k) sm.w[k][t] = f2bf(vv[k] * 0.03f);
    __syncthreads();
    int k = t >> 4, seg = t & 15;
    uint4 val = *reinterpret_cast<const uint4*>(&sm.w[k][seg*8]);
    *reinterpret_cast<uint4*>(Wt + (size_t)q*P_ + (size_t)k*I_ + ch*128 + seg*8) = val;
  } else if (u < 2592){
    int v = u - 1440;
    int tb = v/144, tp = v - tb*144;
    int b0 = tb*32, p0 = tp*64;
    #pragma unroll
    for (int pass = 0; pass < 2; ++pass){
      int vt = t + (pass << 7);
      int r = vt >> 3, c8 = (vt & 7)*8;
      const float* sp = x + (size_t)(b0 + r)*P_ + p0 + c8;
      float4 a = *reinterpret_cast<const float4*>(sp);
      float4 b = *reinterpret_cast<const float4*>(sp + 4);
      *reinterpret_cast<float4*>(&sm.t[r][c8]) = a;
      *reinterpret_cast<float4*>(&sm.t[r][c8+4]) = b;
      uint4 pk;
      pk.x = (unsigned)f2bf(a.x) | ((unsigned)f2bf(a.y) << 16);
      pk.y = (unsigned)f2bf(a.z) | ((unsigned)f2bf(a.w) << 16);
      pk.z = (unsigned)f2bf(b.x) | ((unsigned)f2bf(b.y) << 16);
      pk.w = (unsigned)f2bf(b.z) | ((unsigned)f2bf(b.w) << 16);
      *reinterpret_cast<uint4*>(xbp + (size_t)(b0 + r)*P_ + p0 + c8) = pk;
    }
    __syncthreads();
    #pragma unroll
    for (int pass = 0; pass < 2; ++pass){
      int vt = t + (pass << 7);
      int pc = vt >> 2, rb = (vt & 3)*8;
      uint4 pk;
      pk.x = (unsigned)f2bf(sm.t[rb+0][pc]) | ((unsigned)f2bf(sm.t[rb+1][pc]) << 16);
      pk.y = (unsigned)f2bf(sm.t[rb+2][pc]) | ((unsigned)f2bf(sm.t[rb+3][pc]) << 16);
      pk.z = (unsigned)f2bf(sm.t[rb+4][pc]) | ((unsigned)f2bf(sm.t[rb+5][pc]) << 16);
      pk.w = (unsigned)f2bf(sm.t[rb+6][pc]) | ((unsigned)f2bf(sm.t[rb+7][pc]) << 16);
      *reinterpret_cast<uint4*>(xpb + (size_t)(p0 + pc)*B_ + b0 + rb) = pk;
    }
  } else if (u < 2700){
    bij[(u - 2592)*128 + t] = 0.f;
  } else if (u < 3020){
    sA[(u - 2700)*128 + t] = 0.f;
  } else {
    for (int z = t; z < 4128; z += 128) bar[z] = 0;
  }
}

// ---------------------------------------------------------------------------
// Fence-free monotonic grid barrier, 64 leaves x 20 arrivals -> root(64)
// -> 64 padded release words. All RELAXED agent atomics (MALL, no cache
// maintenance). __syncthreads before arrival drains vmcnt.
// bar: leaf li @ [li*32]; rel li @ [2048+li*32]; root @ [4096].
__device__ inline void gbar(int* bar, int bid, int ph){
  __syncthreads();
  if (threadIdx.x == 0){
    int li = bid & 63;
    if (__hip_atomic_fetch_add(bar + li*32, 1, __ATOMIC_RELAXED,
                               __HIP_MEMORY_SCOPE_AGENT) == ph*20 - 1){
      if (__hip_atomic_fetch_add(bar + 4096, 1, __ATOMIC_RELAXED,
                                 __HIP_MEMORY_SCOPE_AGENT) == ph*64 - 1){
        #pragma unroll
        for (int z = 0; z < 64; ++z)
          __hip_atomic_store(bar + 2048 + z*32, ph, __ATOMIC_RELAXED,
                             __HIP_MEMORY_SCOPE_AGENT);
      }
    }
    while (__hip_atomic_load(bar + 2048 + li*32, __ATOMIC_RELAXED,
                             __HIP_MEMORY_SCOPE_AGENT) < ph)
      __builtin_amdgcn_s_sleep(4);
  }
  __syncthreads();
}

// ---------------------------------------------------------------------------
union LdsU {
  struct { float c[720]; u16 Bt[16][592]; } S;   // 2880 + 18944 = 21824 B
  u16 vl[32][264];                               // 16896 B
};

// C-sub-phase: 9 blocks compute softmax once. bij read via sc0sc1 (MALL,
// atomic-produced); cT written via sc1 stores (MALL) -> consumers plain-read.
__device__ inline void phase_C(int t, int bid,
    const float* __restrict__ bij, float* __restrict__ cT)
{
  if (bid < 9){
    int j = bid*128 + t;
    const float* br = bij + (size_t)j*BIJS;
    f4v a; f4v b4; float2 c2;
    asm volatile(
      "global_load_dwordx4 %0, %3, off sc0 sc1\n\t"
      "global_load_dwordx4 %1, %3, off offset:16 sc0 sc1\n\t"
      "global_load_dwordx2 %2, %3, off offset:32 sc0 sc1\n\t"
      "s_waitcnt vmcnt(0)"
      : "=&v"(a), "=&v"(b4), "=&v"(c2)
      : "v"(br) : "memory");
    float l[10] = {a[0],a[1],a[2],a[3],b4[0],b4[1],b4[2],b4[3],c2.x,c2.y};
    float mx = l[0];
    #pragma unroll
    for (int k = 1; k < 10; ++k) mx = fmaxf(mx, l[k]);
    float e[10]; float se = 0.f;
    #pragma unroll
    for (int k = 0; k < 10; ++k){ e[k] = __expf(l[k]-mx); se += e[k]; }
    float inv = 1.0f / se;
    #pragma unroll
    for (int k = 0; k < 10; ++k) ast1(&cT[k*I_ + j], e[k]*inv);
  }
}

// S phase: kc XCD-affine; c from cT (plain, first touch per buffer);
// Wt/xbp plain (L2-resident).
__device__ inline void phase_S(int t, int bid,
    const u16* __restrict__ xbp, const u16* __restrict__ Wt,
    const float* __restrict__ cT, float* __restrict__ s_cur,
    float* __restrict__ s_zero, LdsU* lds)
{
  int kc = (bid & 7)*2 + ((bid >> 3) & 1);
  int g2 = bid >> 4;                   // 0..79
  int n = g2 % 10, bx2 = g2 / 10;
  if (s_zero && t < 32) ast1(&s_zero[bid*32 + t], 0.f);
  int i0 = (kc & 1)*576;

  // stage c slice (576 contiguous fp32) into swizzled LDS
  const float* cp = cT + (size_t)n*I_ + i0;
  {
    float4 v = *reinterpret_cast<const float4*>(cp + 4*t);
    int d = CIX(4*t);
    lds->S.c[d] = v.x; lds->S.c[d+1] = v.y; lds->S.c[d+2] = v.z; lds->S.c[d+3] = v.w;
    if (t < 16){
      float4 w = *reinterpret_cast<const float4*>(cp + 512 + 4*t);
      int d2 = CIX(512 + 4*t);
      lds->S.c[d2] = w.x; lds->S.c[d2+1] = w.y; lds->S.c[d2+2] = w.z; lds->S.c[d2+3] = w.w;
    }
  }
  __syncthreads();

  // Bt = bf16(Wt * c)
  #pragma unroll
  for (int s9 = 0; s9 < 9; ++s9){
    int uu = t + s9*128;
    int r = uu / 72, m = uu - r*72;
    uint4 w = *reinterpret_cast<const uint4*>(Wt + (size_t)(n*16 + r)*P_ + kc*576 + m*8);
    const float* cc = &lds->S.c[10*m];
    float2 ca = *reinterpret_cast<const float2*>(cc);
    float2 cb = *reinterpret_cast<const float2*>(cc + 2);
    float2 cd = *reinterpret_cast<const float2*>(cc + 4);
    float2 ce = *reinterpret_cast<const float2*>(cc + 6);
    uint4 rr;
    rr.x = (unsigned)f2bf(bf2f(w.x & 0xffff)*ca.x) | ((unsigned)f2bf(bf2f(w.x >> 16)*ca.y) << 16);
    rr.y = (unsigned)f2bf(bf2f(w.y & 0xffff)*cb.x) | ((unsigned)f2bf(bf2f(w.y >> 16)*cb.y) << 16);
    rr.z = (unsigned)f2bf(bf2f(w.z & 0xffff)*cd.x) | ((unsigned)f2bf(bf2f(w.z >> 16)*cd.y) << 16);
    rr.w = (unsigned)f2bf(bf2f(w.w & 0xffff)*ce.x) | ((unsigned)f2bf(bf2f(w.w >> 16)*ce.y) << 16);
    *reinterpret_cast<uint4*>(&lds->S.Bt[r][m*8]) = rr;
  }
  __syncthreads();

  int wid = t >> 6, l = t & 63, lo = l & 15, quad = l >> 4;
  int b0 = bx2*32 + wid*16;
  const s8v* ap = reinterpret_cast<const s8v*>(xbp + (size_t)(b0 + lo)*P_ + kc*576 + quad*8);
  f4v acc0 = {0.f,0.f,0.f,0.f}, acc1 = {0.f,0.f,0.f,0.f};
  #pragma unroll
  for (int s = 0; s < 9; ++s){
    s8v a0 = ap[8*s];
    s8v b0v = *reinterpret_cast<const s8v*>(&lds->S.Bt[lo][quad*8 + 64*s]);
    s8v a1 = ap[8*s + 4];
    s8v b1v = *reinterpret_cast<const s8v*>(&lds->S.Bt[lo][quad*8 + 64*s + 32]);
    acc0 = __builtin_amdgcn_mfma_f32_16x16x32_bf16(a0, b0v, acc0, 0, 0, 0);
    acc1 = __builtin_amdgcn_mfma_f32_16x16x32_bf16(a1, b1v, acc1, 0, 0, 0);
  }
  f4v acc = acc0 + acc1;
  int r0 = quad << 2;
  #pragma unroll
  for (int r = 0; r < 4; ++r)
    atomicAdd(&s_cur[(size_t)(b0 + r0 + r)*NO_ + n*16 + lo], acc[r]);
}

// G phase: s read with PLAIN float4 (first plain touch of that buffer:
// atomicAdd executes at MALL, no L2 copies exist -> fresh). u-map swizzled
// by odd 139 (bijective mod 256) so double-duty tiles spread across XCDs.
__device__ inline void phase_G(int t, int bid,
    const u16* __restrict__ xpb, const float* __restrict__ s,
    const u16* __restrict__ Wt, float* __restrict__ bij, LdsU* lds)
{
  int qp = bid >> 8;                    // 0..4
  #pragma unroll
  for (int h = 0; h < 2; ++h){
    int b = t + (h << 7);
    #pragma unroll
    for (int nn = 0; nn < 2; ++nn){
      const float* sr = s + (size_t)b*NO_ + (qp*2 + nn)*16;
      float4 s0 = *reinterpret_cast<const float4*>(sr);
      float4 s1 = *reinterpret_cast<const float4*>(sr + 4);
      float4 s2 = *reinterpret_cast<const float4*>(sr + 8);
      float4 s3 = *reinterpret_cast<const float4*>(sr + 12);
      float sq = s0.x*s0.x+s0.y*s0.y+s0.z*s0.z+s0.w*s0.w
               + s1.x*s1.x+s1.y*s1.y+s1.z*s1.z+s1.w*s1.w
               + s2.x*s2.x+s2.y*s2.y+s2.z*s2.z+s2.w*s2.w
               + s3.x*s3.x+s3.y*s3.y+s3.z*s3.z+s3.w*s3.w;
      float scale = sqrtf(sq) / (1.0f + sq);
      float sv[16] = {s0.x,s0.y,s0.z,s0.w,s1.x,s1.y,s1.z,s1.w,
                      s2.x,s2.y,s2.z,s2.w,s3.x,s3.y,s3.z,s3.w};
      #pragma unroll
      for (int o = 0; o < 16; ++o)
        lds->vl[nn*16 + o][b] = f2bf(sv[o] * scale);
    }
  }
  __syncthreads();

  int wv = t >> 6, l = t & 63, lo = l & 15, quad = l >> 4;
  int idx = (139*(bid & 255)) & 255;
  for (int u = idx*2 + wv; u < 576; u += 512){
    int p0 = u << 4;
    const s8v* ap = reinterpret_cast<const s8v*>(xpb + (size_t)(p0 + lo)*B_ + quad*8);
    f4v acc0 = {0.f,0.f,0.f,0.f}, acc1 = {0.f,0.f,0.f,0.f};
    #pragma unroll
    for (int st = 0; st < 8; ++st){
      s8v a  = ap[4*st];
      s8v b0 = *reinterpret_cast<const s8v*>(&lds->vl[lo]     [st*32 + quad*8]);
      s8v b1 = *reinterpret_cast<const s8v*>(&lds->vl[16 + lo][st*32 + quad*8]);
      acc0 = __builtin_amdgcn_mfma_f32_16x16x32_bf16(a, b0, acc0, 0, 0, 0);
      acc1 = __builtin_amdgcn_mfma_f32_16x16x32_bf16(a, b1, acc1, 0, 0, 0);
    }
    int ib = p0 % 1152;                 // p-tile never spans k (1152%16==0)
    #pragma unroll
    for (int sb = 0; sb < 2; ++sb){
      f4v acc = sb ? acc1 : acc0;
      int n = qp*2 + sb;
      const u16* wp = Wt + (size_t)(n*16 + lo)*P_ + p0 + (quad << 2);
      ushort4 w4 = *reinterpret_cast<const ushort4*>(wp);
      float v0 = acc[0]*bf2f(w4.x), v1 = acc[1]*bf2f(w4.y);
      float v2 = acc[2]*bf2f(w4.z), v3 = acc[3]*bf2f(w4.w);
      #pragma unroll
      for (int m = 8; m >= 1; m >>= 1){
        v0 += __shfl_xor(v0, m, 16);
        v1 += __shfl_xor(v1, m, 16);
        v2 += __shfl_xor(v2, m, 16);
        v3 += __shfl_xor(v3, m, 16);
      }
      if (lo == 0){
        int i = ib + (quad << 2);
        atomicAdd(&bij[(size_t)(i+0)*BIJS + n], v0 * (1.f/256.f));
        atomicAdd(&bij[(size_t)(i+1)*BIJS + n], v1 * (1.f/256.f));
        atomicAdd(&bij[(size_t)(i+2)*BIJS + n], v2 * (1.f/256.f));
        atomicAdd(&bij[(size_t)(i+3)*BIJS + n], v3 * (1.f/256.f));
      }
    }
  }
}

__global__ __launch_bounds__(128, 3) void k_route(
    const u16* __restrict__ xbp, const u16* __restrict__ xpb,
    const u16* __restrict__ Wt, float* __restrict__ bij,
    float* __restrict__ cTa, float* __restrict__ cTb,
    float* __restrict__ sA, float* __restrict__ sB,
    float* __restrict__ out, int* __restrict__ bar)
{
  __shared__ LdsU lds;
  int t = threadIdx.x, bid = blockIdx.x;

  // ---- iter0 S: c == 0.1 uniform -> s = 0.1*(x . Wt^T). B-frags straight
  // from bf16 Wt, scale in fp32 epilogue. Zeroes sB (sc1: MALL-visible).
  {
    int kc = (bid & 7)*2 + ((bid >> 3) & 1);
    int g2 = bid >> 4;
    int n = g2 % 10, bx2 = g2 / 10;
    if (t < 32) ast1(&sB[bid*32 + t], 0.f);
    int wid = t >> 6, l = t & 63, lo = l & 15, quad = l >> 4;
    int b0 = bx2*32 + wid*16;
    const s8v* ap = reinterpret_cast<const s8v*>(xbp + (size_t)(b0 + lo)*P_ + kc*576 + quad*8);
    const s8v* bp = reinterpret_cast<const s8v*>(Wt  + (size_t)(n*16 + lo)*P_ + kc*576 + quad*8);
    f4v acc0 = {0.f,0.f,0.f,0.f}, acc1 = {0.f,0.f,0.f,0.f};
    #pragma unroll
    for (int s = 0; s < 9; ++s){
      acc0 = __builtin_amdgcn_mfma_f32_16x16x32_bf16(ap[8*s],     bp[8*s],     acc0, 0, 0, 0);
      acc1 = __builtin_amdgcn_mfma_f32_16x16x32_bf16(ap[8*s + 4], bp[8*s + 4], acc1, 0, 0, 0);
    }
    f4v acc = acc0 + acc1;
    int r0 = quad << 2;
    #pragma unroll
    for (int r = 0; r < 4; ++r)
      atomicAdd(&sA[(size_t)(b0 + r0 + r)*NO_ + n*16 + lo], acc[r] * 0.1f);
  }
  gbar(bar, bid, 1);

  phase_G(t, bid, xpb, sA, Wt, bij, &lds);          // iter0 agreement
  gbar(bar, bid, 2);

  phase_C(t, bid, bij, cTa);                        // softmax once -> cTa
  gbar(bar, bid, 3);

  phase_S(t, bid, xbp, Wt, cTa, sB, sA, &lds);      // iter1 s -> sB, zero sA
  gbar(bar, bid, 4);

  phase_G(t, bid, xpb, sB, Wt, bij, &lds);          // iter1 agreement
  gbar(bar, bid, 5);

  phase_C(t, bid, bij, cTb);                        // softmax once -> cTb
  gbar(bar, bid, 6);

  phase_S(t, bid, xbp, Wt, cTb, sA, nullptr, &lds); // iter2 s -> sA
  gbar(bar, bid, 7);

  // ---- final squash -> out (2560 rows of 16; first 320 blocks).
  // sA lines are stale in L2 (cached by G0) -> must bypass (ald1).
  if (bid < 320){
    int o = t & 15, rl = t >> 4;
    int rowid = bid*8 + rl;               // b*10+n
    int b = rowid / 10, n = rowid - b*10;
    size_t idx = (size_t)b*NO_ + n*16 + o;
    float sv = ald1(&sA[idx]);
    float sq = sv * sv;
    #pragma unroll
    for (int m = 8; m >= 1; m >>= 1) sq += __shfl_xor(sq, m, 16);
    out[idx] = sv * sqrtf(sq) / (1.0f + sq);
  }
}

// ---------------------------------------------------------------------------
extern "C" void kernel_launch(void* const* d_in, const int* in_sizes, int n_in,
                              void* d_out, int out_size, void* d_ws, size_t ws_size,
                              hipStream_t stream){
  (void)in_sizes; (void)n_in; (void)out_size; (void)ws_size;
  const float* x = (const float*)d_in[0];   // (256, 8, 1152)
  const float* W = (const float*)d_in[1];   // (1, 1152, 10, 16, 8)
  float* out = (float*)d_out;               // (256, 10, 16, 1) fp32

  float* sA  = (float*)d_ws;                // 40960 fp32
  float* sB  = sA + 40960;                  // 40960
  float* bij = sB + 40960;                  // 13824 (1152 x 12)
  float* cTa = bij + 13824;                 // 11520 (10 x 1152)
  float* cTb = cTa + 11520;                 // 11520
  u16* xbp = (u16*)(cTb + 11520);           // 2359296 bf16
  u16* xpb = xbp + 2359296;                 // 2359296
  u16* Wt  = xpb + 2359296;                 // 1474560
  int* bar = (int*)(Wt + 1474560);          // 4128 ints (barrier state)

  k_prep <<<3021, 128, 0, stream>>>(x, W, xbp, xpb, Wt, bij, sA, bar);
  k_route<<<NBLK, 128, 0, stream>>>(xbp, xpb, Wt, bij, cTa, cTb, sA, sB, out, bar);
}